// Round 1
// baseline (410.966 us; speedup 1.0000x reference)
//
#include <hip/hip_runtime.h>
#include <hip/hip_bf16.h>

// BNN MC-prediction: S=100 weight samples, batch 64, dims 784->512->512->10.
// Strategy: fuse reparameterization sampling (eps*sigma+mean) into bf16-MFMA
// GEMMs; memory-bound on streaming we0/we1 (265 MB). Final layer fp32 VALU.

typedef __bf16 bf16x8 __attribute__((ext_vector_type(8)));
typedef float f32x4 __attribute__((ext_vector_type(4)));

#define NSAMP 100
#define BATCH 64
#define D0 784
#define D1 512
#define D2 512
#define DOUT 10
#define K0PAD 800   // 784 padded to multiple of 32

#define BM 64
#define BN 64
#define BK 32
#define LDK 36      // LDS k-stride in shorts (pad 32->36: 72B rows -> 2-way bank aliasing only)

__device__ __forceinline__ unsigned short f2bf(float f) {
    __bf16 b = (__bf16)f;
    return __builtin_bit_cast(unsigned short, b);
}

union FragU { uint2 d[2]; bf16x8 v; };

// ---------------- precompute: sigma = exp(0.5*logvar), sampled biases, bf16 input ----
#define XB_N   (BATCH * K0PAD)        // 51200
#define SG0_N  (D0 * D1)              // 401408
#define SG1_N  (D1 * D2)              // 262144
#define SGL_N  (D2 * DOUT)            // 5120
#define B0_N   (NSAMP * D1)           // 51200
#define B1_N   (NSAMP * D2)           // 51200
#define BL_N   (NSAMP * DOUT)         // 1000
#define PREP_TOTAL (XB_N + SG0_N + SG1_N + SGL_N + B0_N + B1_N + BL_N)

__global__ __launch_bounds__(256) void prep(
    const float* __restrict__ inputs,
    const float* __restrict__ wv0, const float* __restrict__ wv1,
    const float* __restrict__ wvl,
    const float* __restrict__ be0, const float* __restrict__ bv0, const float* __restrict__ bm0,
    const float* __restrict__ be1, const float* __restrict__ bv1, const float* __restrict__ bm1,
    const float* __restrict__ bel, const float* __restrict__ bvl, const float* __restrict__ bml,
    unsigned short* __restrict__ Xb, float* __restrict__ sigma0,
    float* __restrict__ sigma1, float* __restrict__ sigmal,
    float* __restrict__ bias0, float* __restrict__ bias1, float* __restrict__ biasl)
{
    int i = blockIdx.x * 256 + threadIdx.x;
    if (i < XB_N) {
        int m = i / K0PAD, k = i % K0PAD;
        float v = (k < D0) ? inputs[m * D0 + k] : 0.f;
        Xb[i] = f2bf(v);
        return;
    }
    i -= XB_N;
    if (i < SG0_N) { sigma0[i] = __expf(0.5f * wv0[i]); return; }
    i -= SG0_N;
    if (i < SG1_N) { sigma1[i] = __expf(0.5f * wv1[i]); return; }
    i -= SG1_N;
    if (i < SGL_N) { sigmal[i] = __expf(0.5f * wvl[i]); return; }
    i -= SGL_N;
    if (i < B0_N) { int n = i % D1; bias0[i] = fmaf(be0[i], __expf(0.5f * bv0[n]), bm0[n]); return; }
    i -= B0_N;
    if (i < B1_N) { int n = i % D2; bias1[i] = fmaf(be1[i], __expf(0.5f * bv1[n]), bm1[n]); return; }
    i -= B1_N;
    if (i < BL_N) { int o = i % DOUT; biasl[i] = fmaf(bel[i], __expf(0.5f * bvl[o]), bml[o]); return; }
}

// ---------------- fused sampling + bf16 MFMA GEMM (layers 0 and 1) ----------------
// out[s][m][n] = relu( sum_k A[s][m][k] * (eps[s][k][n]*sigma[k][n]+mean[k][n]) + bias[s][n] )
__global__ __launch_bounds__(256) void gemm_layer(
    const unsigned short* __restrict__ A, int lda, long aStride,   // bf16 A, [.. ][BATCH][lda]
    const float* __restrict__ eps, long eStride,                   // [S][Kvalid][N]
    const float* __restrict__ sigma, const float* __restrict__ mean, // [Kvalid][N]
    int N, int K, int Kvalid,
    const float* __restrict__ bias,                                // [S][N]
    void* __restrict__ outp, int outBf16)                          // [S][BATCH][N]
{
    __shared__ unsigned short smA[BM * LDK];
    __shared__ unsigned short smB[BN * LDK];

    const int s  = blockIdx.y;
    const int n0 = blockIdx.x * BN;
    const int t  = threadIdx.x;

    const unsigned short* As = A + (long)s * aStride;
    const float* epsS = eps + (long)s * eStride;

    // A staging: each thread loads 8 contiguous bf16 (one uint4)
    const int am = t >> 2;
    const int ac = (t & 3) * 8;
    // B staging: each thread covers n = t&63, k = (t>>6)*8 + j (j=0..7)
    const int bn  = t & 63;
    const int bk0 = (t >> 6) * 8;

    const int lane = t & 63;
    const int w    = t >> 6;
    const int mbase = (w & 1) * 32;
    const int nbase = (w >> 1) * 32;
    const int fr   = lane & 15;
    const int quad = lane >> 4;

    f32x4 acc[2][2] = {};
    const int KT = K / BK;

    uint4 pa;
    float pe[8], ps[8], pm[8];

    // prefetch kt = 0
    {
        pa = *reinterpret_cast<const uint4*>(As + (long)am * lda + ac);
#pragma unroll
        for (int j = 0; j < 8; ++j) {
            int k = bk0 + j;
            long off = (long)k * N + n0 + bn;
            bool v = k < Kvalid;
            pe[j] = v ? epsS[off] : 0.f;
            ps[j] = v ? sigma[off] : 0.f;
            pm[j] = v ? mean[off] : 0.f;
        }
    }

    for (int kt = 0; kt < KT; ++kt) {
        __syncthreads();   // previous compute done with LDS
        // ---- write A tile ----
        {
            unsigned short* dst = &smA[am * LDK + ac];
            uint2 w0; w0.x = pa.x; w0.y = pa.y;
            uint2 w1; w1.x = pa.z; w1.y = pa.w;
            reinterpret_cast<uint2*>(dst)[0] = w0;
            *reinterpret_cast<uint2*>(dst + 4) = w1;
        }
        // ---- transform + write B tile (stored [n][k], k-contiguous) ----
        {
            unsigned int p01, p23, p45, p67;
            p01 = (unsigned int)f2bf(fmaf(pe[0], ps[0], pm[0])) |
                  ((unsigned int)f2bf(fmaf(pe[1], ps[1], pm[1])) << 16);
            p23 = (unsigned int)f2bf(fmaf(pe[2], ps[2], pm[2])) |
                  ((unsigned int)f2bf(fmaf(pe[3], ps[3], pm[3])) << 16);
            p45 = (unsigned int)f2bf(fmaf(pe[4], ps[4], pm[4])) |
                  ((unsigned int)f2bf(fmaf(pe[5], ps[5], pm[5])) << 16);
            p67 = (unsigned int)f2bf(fmaf(pe[6], ps[6], pm[6])) |
                  ((unsigned int)f2bf(fmaf(pe[7], ps[7], pm[7])) << 16);
            unsigned short* dst = &smB[bn * LDK + bk0];
            uint2 w0; w0.x = p01; w0.y = p23;
            uint2 w1; w1.x = p45; w1.y = p67;
            reinterpret_cast<uint2*>(dst)[0] = w0;
            *reinterpret_cast<uint2*>(dst + 4) = w1;
        }
        // ---- prefetch next iteration's globals (overlap with compute below) ----
        if (kt + 1 < KT) {
            const int kg = (kt + 1) * BK;
            pa = *reinterpret_cast<const uint4*>(As + (long)am * lda + kg + ac);
#pragma unroll
            for (int j = 0; j < 8; ++j) {
                int k = kg + bk0 + j;
                long off = (long)k * N + n0 + bn;
                bool v = k < Kvalid;
                pe[j] = v ? epsS[off] : 0.f;
                ps[j] = v ? sigma[off] : 0.f;
                pm[j] = v ? mean[off] : 0.f;
            }
        }
        __syncthreads();   // tiles visible
        // ---- MFMA: 2x2 subtiles of 16x16, K=32 per instruction ----
        FragU af[2], bf[2];
#pragma unroll
        for (int mi = 0; mi < 2; ++mi) {
            const unsigned short* p = &smA[(mbase + mi * 16 + fr) * LDK + quad * 8];
            const uint2* q = reinterpret_cast<const uint2*>(p);
            af[mi].d[0] = q[0]; af[mi].d[1] = q[1];
        }
#pragma unroll
        for (int ni = 0; ni < 2; ++ni) {
            const unsigned short* p = &smB[(nbase + ni * 16 + fr) * LDK + quad * 8];
            const uint2* q = reinterpret_cast<const uint2*>(p);
            bf[ni].d[0] = q[0]; bf[ni].d[1] = q[1];
        }
#pragma unroll
        for (int mi = 0; mi < 2; ++mi)
#pragma unroll
            for (int ni = 0; ni < 2; ++ni)
                acc[mi][ni] = __builtin_amdgcn_mfma_f32_16x16x32_bf16(
                    af[mi].v, bf[ni].v, acc[mi][ni], 0, 0, 0);
    }

    // ---- epilogue: bias + relu, store bf16 or f32 ----
    const long outBase = (long)s * BATCH * N;
#pragma unroll
    for (int mi = 0; mi < 2; ++mi) {
#pragma unroll
        for (int ni = 0; ni < 2; ++ni) {
            const int col = n0 + nbase + ni * 16 + fr;
            const float bv = bias[(long)s * N + col];
#pragma unroll
            for (int r = 0; r < 4; ++r) {
                const int row = mbase + mi * 16 + quad * 4 + r;
                float v = acc[mi][ni][r] + bv;
                v = fmaxf(v, 0.f);
                const long idx = outBase + (long)row * N + col;
                if (outBf16) ((unsigned short*)outp)[idx] = f2bf(v);
                else         ((float*)outp)[idx] = v;
            }
        }
    }
}

// ---------------- final layer: [64,512] @ [512,10] + bias, fp32 VALU ----------------
__global__ __launch_bounds__(320) void last_layer(
    const float* __restrict__ act2,   // [S][64][512]
    const float* __restrict__ wel,    // [S][512][10]
    const float* __restrict__ sigmal, // [512][10]
    const float* __restrict__ wml,    // [512][10]
    const float* __restrict__ biasl,  // [S][10]
    float* __restrict__ out)          // [S][64][10]
{
    __shared__ float smW[D2 * DOUT];  // 20 KB
    const int s = blockIdx.x;
    const int t = threadIdx.x;
    const float* we = wel + (long)s * D2 * DOUT;
    for (int i = t; i < D2 * DOUT; i += 320)
        smW[i] = fmaf(we[i], sigmal[i], wml[i]);
    __syncthreads();

    const int m  = t / 5;
    const int op = t % 5;
    const float* a = act2 + ((long)s * BATCH + m) * D2;
    float acc0 = 0.f, acc1 = 0.f;
#pragma unroll 4
    for (int k = 0; k < D2; k += 4) {
        float4 av = *reinterpret_cast<const float4*>(a + k);
        acc0 = fmaf(av.x, smW[(k + 0) * DOUT + op], acc0);
        acc0 = fmaf(av.y, smW[(k + 1) * DOUT + op], acc0);
        acc0 = fmaf(av.z, smW[(k + 2) * DOUT + op], acc0);
        acc0 = fmaf(av.w, smW[(k + 3) * DOUT + op], acc0);
        acc1 = fmaf(av.x, smW[(k + 0) * DOUT + op + 5], acc1);
        acc1 = fmaf(av.y, smW[(k + 1) * DOUT + op + 5], acc1);
        acc1 = fmaf(av.z, smW[(k + 2) * DOUT + op + 5], acc1);
        acc1 = fmaf(av.w, smW[(k + 3) * DOUT + op + 5], acc1);
    }
    const long ob = ((long)s * BATCH + m) * DOUT;
    out[ob + op]     = acc0 + biasl[s * DOUT + op];
    out[ob + op + 5] = acc1 + biasl[s * DOUT + op + 5];
}

extern "C" void kernel_launch(void* const* d_in, const int* in_sizes, int n_in,
                              void* d_out, int out_size, void* d_ws, size_t ws_size,
                              hipStream_t stream)
{
    const float* inputs = (const float*)d_in[0];
    // d_in[1] = task_id (unused; single head in reference)
    const float* wm0 = (const float*)d_in[2];
    const float* wv0 = (const float*)d_in[3];
    const float* bm0 = (const float*)d_in[4];
    const float* bv0 = (const float*)d_in[5];
    const float* wm1 = (const float*)d_in[6];
    const float* wv1 = (const float*)d_in[7];
    const float* bm1 = (const float*)d_in[8];
    const float* bv1 = (const float*)d_in[9];
    const float* wml = (const float*)d_in[10];
    const float* wvl = (const float*)d_in[11];
    const float* bml = (const float*)d_in[12];
    const float* bvl = (const float*)d_in[13];
    const float* we0 = (const float*)d_in[14];
    const float* be0 = (const float*)d_in[15];
    const float* we1 = (const float*)d_in[16];
    const float* be1 = (const float*)d_in[17];
    const float* wel = (const float*)d_in[18];
    const float* bel = (const float*)d_in[19];

    // workspace carve (total ~22.9 MB)
    char* w = (char*)d_ws;
    unsigned short* Xb = (unsigned short*)w; w += (size_t)XB_N * 2;
    float* sigma0 = (float*)w; w += (size_t)SG0_N * 4;
    float* sigma1 = (float*)w; w += (size_t)SG1_N * 4;
    float* sigmal = (float*)w; w += (size_t)SGL_N * 4;
    float* bias0  = (float*)w; w += (size_t)B0_N * 4;
    float* bias1  = (float*)w; w += (size_t)B1_N * 4;
    float* biasl  = (float*)w; w += (size_t)BL_N * 4;
    unsigned short* act1 = (unsigned short*)w; w += (size_t)NSAMP * BATCH * D1 * 2;
    float* act2 = (float*)w; w += (size_t)NSAMP * BATCH * D2 * 4;

    prep<<<dim3((PREP_TOTAL + 255) / 256), 256, 0, stream>>>(
        inputs, wv0, wv1, wvl, be0, bv0, bm0, be1, bv1, bm1, bel, bvl, bml,
        Xb, sigma0, sigma1, sigmal, bias0, bias1, biasl);

    // layer 0: A = Xb (shared across samples), K padded 800 (A zero-padded)
    gemm_layer<<<dim3(D1 / BN, NSAMP), 256, 0, stream>>>(
        Xb, K0PAD, 0L, we0, (long)D0 * D1, sigma0, wm0,
        D1, K0PAD, D0, bias0, (void*)act1, 1);

    // layer 1
    gemm_layer<<<dim3(D2 / BN, NSAMP), 256, 0, stream>>>(
        act1, D1, (long)BATCH * D1, we1, (long)D1 * D2, sigma1, wm1,
        D2, D1, D1, bias1, (void*)act2, 0);

    last_layer<<<dim3(NSAMP), 320, 0, stream>>>(
        act2, wel, sigmal, wml, biasl, (float*)d_out);
}